// Round 8
// baseline (1175.856 us; speedup 1.0000x reference)
//
#include <hip/hip_runtime.h>
#include <math.h>

#define NB 8
#define D 512
#define H 8
#define DH 64
#define NSEG 16
#define RT 64
#define UU 256
#define QN 336
#define KN 335
#define SROWS 320
#define FFN_D 2048
#define LAYERS 8
#define OUTD 1024
#define TR 260
#define NEGV (-100000000.0f)
#define QSCALE 0.125f

typedef __attribute__((ext_vector_type(8))) short bf16x8;
typedef __attribute__((ext_vector_type(4))) float f32x4;

__device__ inline unsigned short f2bf(float f) {
    union { float f; unsigned int u; } v; v.f = f;
    unsigned int u = v.u;
    unsigned int r = (u + 0x7FFFu + ((u >> 16) & 1u)) >> 16;
    return (unsigned short)r;
}
__device__ inline float bf2f(unsigned short h) {
    union { unsigned int u; float f; } v; v.u = ((unsigned int)h) << 16;
    return v.f;
}

// 16-byte global -> LDS async DMA. LDS dest = wave-uniform base + lane*16.
__device__ inline void async16(const void* g, void* l) {
    __builtin_amdgcn_global_load_lds((const __attribute__((address_space(1))) void*)g,
                                     (__attribute__((address_space(3))) void*)l, 16, 0, 0);
}

// ---------------- lr + max ----------------
__global__ void lr_k(const int* __restrict__ lengths, int* __restrict__ lrw,
                     float* __restrict__ out_lr) {
    if (threadIdx.x == 0) {
        int mx = 0;
        for (int b = 0; b < NB; ++b) {
            int v = lengths[b] >> 2;
            lrw[b] = v;
            out_lr[b] = (float)v;
            if (v > mx) mx = v;
        }
        lrw[NB] = mx;
    }
}

// ---------------- input projection + reshape to (t,b,512) ----------------
__global__ __launch_bounds__(128) void inproj_k(const float* __restrict__ input,
                                                const float* __restrict__ w_in,
                                                float* __restrict__ XB) {
    __shared__ float wl[80 * 128];
    __shared__ float il[4 * 80];
    int tid = threadIdx.x;
    int t = blockIdx.x >> 3;
    int b = blockIdx.x & 7;
    for (int i = tid; i < 80 * 128; i += 128) wl[i] = w_in[i];
    const float* inp = input + ((size_t)b * 1040 + (size_t)t * 4) * 80;
    for (int i = tid; i < 320; i += 128) il[i] = inp[i];
    __syncthreads();
    float* xrow = XB + ((size_t)(t * NB + b)) * D;
#pragma unroll
    for (int c = 0; c < 4; ++c) {
        float acc = 0.f;
        for (int i = 0; i < 80; ++i) acc = fmaf(il[c * 80 + i], wl[i * 128 + tid], acc);
        xrow[c * 128 + tid] = acc;
    }
}

// ---------------- init state S = [rc(64), utt(256)] (fp32) ----------------
__global__ __launch_bounds__(256) void initstate_k(const float* __restrict__ XB,
                                                   float* __restrict__ S) {
    int r = blockIdx.x;
    int srow = r >> 3, b = r & 7;
    int src;
    if (srow < RT) {
        int i = srow >> 2, jj = srow & 3;
        src = (i < 15 ? (i + 1) * 16 : 256) + jj;
    } else {
        src = srow - RT;
    }
    const float* xr = XB + ((size_t)(src * NB + b)) * D;
    float* sr = S + (size_t)r * D;
    sr[threadIdx.x] = xr[threadIdx.x];
    sr[threadIdx.x + 256] = xr[threadIdx.x + 256];
}

// ---------------- initial mems -> bf16 ----------------
__global__ __launch_bounds__(256) void mems0_k(const float* __restrict__ XB,
                                               unsigned short* __restrict__ MEMS) {
    int ib = blockIdx.x;
    int i = ib >> 3, b = ib & 7;
    for (int c = 0; c < 2; ++c) {
        int col = threadIdx.x + c * 256;
        float s = 0.f;
#pragma unroll
        for (int t = 0; t < 16; ++t) s += XB[((size_t)((i * 16 + t) * NB + b)) * D + col];
        MEMS[(size_t)ib * D + col] = f2bf(s * (1.f / 16.f));
    }
}

// ---------------- fused double-LayerNorm ----------------
// fused=0: Y16 = LN_A(X), X untouched.
// fused=1: t = LN_A(X); X = t; Y16 = LN_B(t).
__global__ __launch_bounds__(256) void ln2_k(float* __restrict__ X,
                                             unsigned short* __restrict__ Y16,
                                             const float* __restrict__ gA,
                                             const float* __restrict__ bA,
                                             const float* __restrict__ gB,
                                             const float* __restrict__ bB, int fused) {
    int row = blockIdx.x;
    float* x = X + (size_t)row * D;
    __shared__ float rs_[4], rss_[4], rs2[4], rss2[4];
    int w = threadIdx.x >> 6;
    float v[2];
    float s = 0.f, ss = 0.f;
#pragma unroll
    for (int j = 0; j < 2; ++j) {
        v[j] = x[threadIdx.x + j * 256];
        s += v[j];
        ss = fmaf(v[j], v[j], ss);
    }
#pragma unroll
    for (int off = 32; off; off >>= 1) {
        s += __shfl_xor(s, off);
        ss += __shfl_xor(ss, off);
    }
    if ((threadIdx.x & 63) == 0) { rs_[w] = s; rss_[w] = ss; }
    __syncthreads();
    s = rs_[0] + rs_[1] + rs_[2] + rs_[3];
    ss = rss_[0] + rss_[1] + rss_[2] + rss_[3];
    float mean = s * (1.f / D);
    float var = ss * (1.f / D) - mean * mean;
    float rstd = rsqrtf(var + 1e-5f);
    float y1[2];
#pragma unroll
    for (int j = 0; j < 2; ++j) {
        int col = threadIdx.x + j * 256;
        y1[j] = (v[j] - mean) * rstd * gA[col] + bA[col];
    }
    if (!fused) {
#pragma unroll
        for (int j = 0; j < 2; ++j)
            Y16[(size_t)row * D + threadIdx.x + j * 256] = f2bf(y1[j]);
        return;
    }
    float s2 = 0.f, ss2 = 0.f;
#pragma unroll
    for (int j = 0; j < 2; ++j) {
        s2 += y1[j];
        ss2 = fmaf(y1[j], y1[j], ss2);
    }
#pragma unroll
    for (int off = 32; off; off >>= 1) {
        s2 += __shfl_xor(s2, off);
        ss2 += __shfl_xor(ss2, off);
    }
    if ((threadIdx.x & 63) == 0) { rs2[w] = s2; rss2[w] = ss2; }
    __syncthreads();
    s2 = rs2[0] + rs2[1] + rs2[2] + rs2[3];
    ss2 = rss2[0] + rss2[1] + rss2[2] + rss2[3];
    float mean2 = s2 * (1.f / D);
    float var2 = ss2 * (1.f / D) - mean2 * mean2;
    float rstd2 = rsqrtf(var2 + 1e-5f);
#pragma unroll
    for (int j = 0; j < 2; ++j) {
        int col = threadIdx.x + j * 256;
        x[col] = y1[j];
        Y16[(size_t)row * D + col] = f2bf((y1[j] - mean2) * rstd2 * gB[col] + bB[col]);
    }
}

// ---------------- residual add + LN + mems-tanh fused ----------------
__global__ __launch_bounds__(256) void ln_res_k(const float* __restrict__ OUTB,
                                                float* __restrict__ SB,
                                                unsigned short* __restrict__ MEMS,
                                                unsigned short* __restrict__ Y16,
                                                const float* __restrict__ g,
                                                const float* __restrict__ be) {
    int row = blockIdx.x;
    if (row >= SROWS * NB) {
        int j = row - SROWS * NB;
#pragma unroll
        for (int c = 0; c < 2; ++c) {
            int col = threadIdx.x + c * 256;
            MEMS[(size_t)j * D + col] = f2bf(tanhf(OUTB[(size_t)row * D + col]));
        }
        return;
    }
    float v[2];
    float s = 0.f, ss = 0.f;
#pragma unroll
    for (int j = 0; j < 2; ++j) {
        int col = threadIdx.x + j * 256;
        float r = SB[(size_t)row * D + col] + OUTB[(size_t)row * D + col];
        SB[(size_t)row * D + col] = r;
        v[j] = r;
        s += r;
        ss = fmaf(r, r, ss);
    }
#pragma unroll
    for (int off = 32; off; off >>= 1) {
        s += __shfl_xor(s, off);
        ss += __shfl_xor(ss, off);
    }
    __shared__ float rs_[4], rss_[4];
    int w = threadIdx.x >> 6;
    if ((threadIdx.x & 63) == 0) {
        rs_[w] = s;
        rss_[w] = ss;
    }
    __syncthreads();
    s = rs_[0] + rs_[1] + rs_[2] + rs_[3];
    ss = rss_[0] + rss_[1] + rss_[2] + rss_[3];
    float mean = s * (1.f / D);
    float var = ss * (1.f / D) - mean * mean;
    float rstd = rsqrtf(var + 1e-5f);
#pragma unroll
    for (int j = 0; j < 2; ++j) {
        int col = threadIdx.x + j * 256;
        Y16[(size_t)row * D + col] = f2bf((v[j] - mean) * rstd * g[col] + be[col]);
    }
}

// ---------------- 64x64 transpose + fp32->bf16 convert helper ----------------
__device__ inline void conv_tile64(float (*tile)[65], const float* __restrict__ src, int srcN,
                                   int k0, int sn0, unsigned short* __restrict__ dst, int dstK,
                                   int dn0) {
    int t = threadIdx.x;
#pragma unroll
    for (int p = 0; p < 4; ++p) {
        int r = p * 16 + (t >> 4);
        int c = (t & 15) * 4;
        *(float4*)&tile[r][c] = *(const float4*)&src[(size_t)(k0 + r) * srcN + sn0 + c];
    }
    __syncthreads();
#pragma unroll
    for (int p = 0; p < 2; ++p) {
        int rn = p * 32 + (t >> 3);
        int kc = (t & 7) * 8;
        int4 o;
        o.x = (int)f2bf(tile[kc + 0][rn]) | ((int)f2bf(tile[kc + 1][rn]) << 16);
        o.y = (int)f2bf(tile[kc + 2][rn]) | ((int)f2bf(tile[kc + 3][rn]) << 16);
        o.z = (int)f2bf(tile[kc + 4][rn]) | ((int)f2bf(tile[kc + 5][rn]) << 16);
        o.w = (int)f2bf(tile[kc + 6][rn]) | ((int)f2bf(tile[kc + 7][rn]) << 16);
        *(int4*)&dst[(size_t)(dn0 + rn) * dstK + k0 + kc] = o;
    }
    __syncthreads();
}

// ---------------- ALL-layer weight conversion (one shot): fp32 KxN -> bf16 NxK ----------
__global__ __launch_bounds__(256) void convw_all_k(const float* __restrict__ wq,
                                                   const float* __restrict__ wk,
                                                   const float* __restrict__ wv,
                                                   const float* __restrict__ wo,
                                                   const float* __restrict__ w1,
                                                   const float* __restrict__ w2,
                                                   const float* __restrict__ bq,
                                                   const float* __restrict__ bk,
                                                   const float* __restrict__ bv,
                                                   const float* __restrict__ w_out,
                                                   unsigned short* __restrict__ WQKV,
                                                   unsigned short* __restrict__ WO16,
                                                   unsigned short* __restrict__ W1T,
                                                   unsigned short* __restrict__ W2T,
                                                   unsigned short* __restrict__ WOUT16,
                                                   float* __restrict__ BQKV) {
    __shared__ float tile[64][65];
    int tb = blockIdx.x;
    if (tb >= LAYERS * 768) {
        int t = tb - LAYERS * 768;
        int n0 = (t % 16) * 64, k0 = (t / 16) * 64;
        conv_tile64(tile, w_out, 1024, k0, n0, WOUT16, 512, n0);
        return;
    }
    int l = tb / 768, t = tb % 768;
    if (t == 0) {
        for (int i = threadIdx.x; i < 1536; i += 256)
            BQKV[l * 1536 + i] = i < 512 ? bq[l * 512 + i]
                                         : (i < 1024 ? bk[l * 512 + i - 512]
                                                     : bv[l * 512 + i - 1024]);
    }
    if (t < 192) {
        int n0 = (t % 24) * 64, k0 = (t / 24) * 64;
        const float* src;
        int sn0;
        if (n0 < 512) { src = wq + (size_t)l * 262144; sn0 = n0; }
        else if (n0 < 1024) { src = wk + (size_t)l * 262144; sn0 = n0 - 512; }
        else { src = wv + (size_t)l * 262144; sn0 = n0 - 1024; }
        conv_tile64(tile, src, 512, k0, sn0, WQKV + (size_t)l * 1536 * 512, 512, n0);
    } else if (t < 256) {
        int tt = t - 192;
        int n0 = (tt % 8) * 64, k0 = (tt / 8) * 64;
        conv_tile64(tile, wo + (size_t)l * 262144, 512, k0, n0, WO16 + (size_t)l * 512 * 512, 512,
                    n0);
    } else if (t < 512) {
        int tt = t - 256;
        int n0 = (tt % 32) * 64, k0 = (tt / 32) * 64;
        conv_tile64(tile, w1 + (size_t)l * 1048576, 2048, k0, n0, W1T + (size_t)l * 2048 * 512,
                    512, n0);
    } else {
        int tt = t - 512;
        int n0 = (tt % 8) * 64, k0 = (tt / 8) * 64;
        conv_tile64(tile, w2 + (size_t)l * 1048576, 512, k0, n0, W2T + (size_t)l * 512 * 2048,
                    2048, n0);
    }
}

// ---------------- bf16 MFMA GEMM, 64x64 tile, BK=64, LDS double-buffer + async DMA ------
// Pipeline: issue DMA(tile it+1) AFTER the barrier that drained tile it, BEFORE compute(it)
// -> the DMA is in flight during the whole compute phase; one barrier per K-iteration.
// flags: 1 = relu, 2 = add into fp32 C, 4 = bf16 output, 8 = atomicAdd into fp32 C
__global__ __launch_bounds__(256) void gemm16_k(const unsigned short* __restrict__ A,
                                                const unsigned short* __restrict__ BT,
                                                const float* __restrict__ bias,
                                                void* __restrict__ Cp, int M, int N, int K,
                                                int Kchunk, int flags) {
    __shared__ unsigned short As[2 * 64 * 64];
    __shared__ unsigned short Bs[2 * 64 * 64];
    int tid = threadIdx.x;
    int wave = tid >> 6, lane = tid & 63;
    int wm = wave >> 1, wn = wave & 1;
    int quad = lane >> 4, sub = lane & 15;
    int m0 = blockIdx.y * 64, n0 = blockIdx.x * 64;
    int kb = blockIdx.z * Kchunk;

    // staging: wave covers LDS slots [wave*128, wave*128+128); slot s = row*8 + chunk
    int s0 = wave * 128 + lane;
    int s1 = s0 + 64;
    int r0 = s0 >> 3, c0 = (s0 & 7) ^ (r0 & 7);
    int r1 = s1 >> 3, c1 = (s1 & 7) ^ (r1 & 7);
    int gra0 = m0 + r0; if (gra0 >= M) gra0 = M - 1;  // clamp: stores row-guarded
    int gra1 = m0 + r1; if (gra1 >= M) gra1 = M - 1;
    const unsigned short* gA0 = A + (size_t)gra0 * K + kb + c0 * 8;
    const unsigned short* gA1 = A + (size_t)gra1 * K + kb + c1 * 8;
    const unsigned short* gB0 = BT + (size_t)(n0 + r0) * K + kb + c0 * 8;
    const unsigned short* gB1 = BT + (size_t)(n0 + r1) * K + kb + c1 * 8;
    int lo0 = (wave * 128) * 8;
    int lo1 = (wave * 128 + 64) * 8;

    int rowA0 = wm * 32 + sub, rowA1 = rowA0 + 16;
    int rowB0 = wn * 32 + sub, rowB1 = rowB0 + 16;

    int nIter = Kchunk >> 6;
    f32x4 acc[2][2] = {};

    // prologue: tile 0 -> buffer 0
    async16(gA0, &As[lo0]);
    async16(gA1, &As[lo1]);
    async16(gB0, &Bs[lo0]);
    async16(gB1, &Bs[lo1]);

    for (int it = 0; it < nIter; ++it) {
        __syncthreads();  // drains DMA of tile it (in flight during previous compute)
        int bo = (it & 1) * 4096;
        if (it + 1 < nIter) {
            int nb = ((it + 1) & 1) * 4096;
            int ko = (it + 1) * 64;
            async16(gA0 + ko, &As[nb + lo0]);
            async16(gA1 + ko, &As[nb + lo1]);
            async16(gB0 + ko, &Bs[nb + lo0]);
            async16(gB1 + ko, &Bs[nb + lo1]);
        }
#pragma unroll
        for (int ks = 0; ks < 2; ++ks) {
            int cc = ks * 4 + quad;
            bf16x8 af0 = *(const bf16x8*)&As[bo + rowA0 * 64 + ((cc ^ (rowA0 & 7)) * 8)];
            bf16x8 af1 = *(const bf16x8*)&As[bo + rowA1 * 64 + ((cc ^ (rowA1 & 7)) * 8)];
            bf16x8 bf0 = *(const bf16x8*)&Bs[bo + rowB0 * 64 + ((cc ^ (rowB0 & 7)) * 8)];
            bf16x8 bf1 = *(const bf16x8*)&Bs[bo + rowB1 * 64 + ((cc ^ (rowB1 & 7)) * 8)];
            acc[0][0] = __builtin_amdgcn_mfma_f32_16x16x32_bf16(af0, bf0, acc[0][0], 0, 0, 0);
            acc[0][1] = __builtin_amdgcn_mfma_f32_16x16x32_bf16(af0, bf1, acc[0][1], 0, 0, 0);
            acc[1][0] = __builtin_amdgcn_mfma_f32_16x16x32_bf16(af1, bf0, acc[1][0], 0, 0, 0);
            acc[1][1] = __builtin_amdgcn_mfma_f32_16x16x32_bf16(af1, bf1, acc[1][1], 0, 0, 0);
        }
    }

    bool relu = flags & 1, addc = flags & 2, obf = flags & 4, atom = flags & 8;
    bool addbias = !atom || blockIdx.z == 0;
    float* Cf = (float*)Cp;
    unsigned short* Ch = (unsigned short*)Cp;
#pragma unroll
    for (int mi = 0; mi < 2; ++mi) {
#pragma unroll
        for (int ni = 0; ni < 2; ++ni) {
#pragma unroll
            for (int r = 0; r < 4; ++r) {
                int row = m0 + wm * 32 + mi * 16 + quad * 4 + r;
                int col = n0 + wn * 32 + ni * 16 + sub;
                if (row < M) {
                    float v = acc[mi][ni][r] + (addbias ? bias[col] : 0.f);
                    if (relu) v = fmaxf(v, 0.f);
                    size_t idx = (size_t)row * N + col;
                    if (obf) {
                        Ch[idx] = f2bf(v);
                    } else if (atom) {
                        atomicAdd(&Cf[idx], v);
                    } else {
                        if (addc) v += Cf[idx];
                        Cf[idx] = v;
                    }
                }
            }
        }
    }
}

// ---------------- attention: one 256-thread block per (qrow, b), all 8 heads -------------
// Summary (is_sum) q-rows are computed on the fly as the mean of the 16 utt Q rows
// (mean(x)@Wq + bq == mean(x@Wq + bq)), so no summary GEMM rows are needed.
__global__ __launch_bounds__(256) void attn_k(const unsigned short* __restrict__ QKV,
                                              unsigned short* __restrict__ ATT,
                                              const int* __restrict__ lrw) {
    int tid = threadIdx.x;
    int qrow = blockIdx.x;
    int b = blockIdx.y;

    int i, is_sum;
    if (qrow < RT) {
        i = qrow >> 2;
        is_sum = 0;
    } else if (qrow < RT + UU) {
        i = (qrow - RT) >> 4;
        is_sum = 0;
    } else {
        i = qrow - (RT + UU);
        is_sum = 1;
    }
    int ms = (i > 4) ? (i - 4) : 0;
    int n_mem = is_sum ? 0 : (i - ms);
    int us = (i * 16 - 32 > 0) ? (i * 16 - 32) : 0;
    int ue = (i + 1) * 16;
    int total = n_mem + 4 + (ue - us);
    int klen = KN + lrw[b] - lrw[NB];

    __shared__ float qs[512];
    __shared__ float sc[H][64];
    __shared__ int kks[64];

    if (!is_sum) {
        const unsigned int* qrp =
            (const unsigned int*)&QKV[(size_t)(120 + qrow * NB + b) * 1536];
        unsigned int u = qrp[tid];
        qs[2 * tid] = __uint_as_float(u << 16) * QSCALE;
        qs[2 * tid + 1] = __uint_as_float(u & 0xFFFF0000u) * QSCALE;
    } else {
        const unsigned int* qrp =
            (const unsigned int*)&QKV[(size_t)(120 + (RT + i * 16) * NB + b) * 1536];
        float a0 = 0.f, a1 = 0.f;
#pragma unroll
        for (int t = 0; t < 16; ++t) {
            unsigned int u = qrp[(size_t)t * (NB * 768) + tid];
            a0 += __uint_as_float(u << 16);
            a1 += __uint_as_float(u & 0xFFFF0000u);
        }
        qs[2 * tid] = a0 * (QSCALE / 16.f);
        qs[2 * tid + 1] = a1 * (QSCALE / 16.f);
    }
    if (tid < 64) {
        int kk = -1;
        if (tid < total) {
            if (tid < n_mem)
                kk = ms + tid;
            else if (tid < n_mem + 4)
                kk = 15 + i * 4 + (tid - n_mem);
            else
                kk = 79 + us + (tid - n_mem - 4);
        }
        kks[tid] = kk;
    }
    __syncthreads();

#pragma unroll
    for (int rep = 0; rep < 2; ++rep) {
        int p = rep * 256 + tid;
        int h = p >> 6, j = p & 63;
        int kk = kks[j];
        float s = NEGV;
        if (kk >= 0 && kk < klen) {
            const int4* kr = (const int4*)&QKV[(size_t)(kk * NB + b) * 1536 + 512 + h * DH];
            const float* qh = &qs[h * DH];
            float accd = 0.f;
#pragma unroll
            for (int c = 0; c < 8; ++c) {
                int4 kv = kr[c];
                const int uu[4] = {kv.x, kv.y, kv.z, kv.w};
#pragma unroll
                for (int jj = 0; jj < 4; ++jj) {
                    float lo = __uint_as_float(((unsigned)uu[jj]) << 16);
                    float hi = __uint_as_float(((unsigned)uu[jj]) & 0xFFFF0000u);
                    accd = fmaf(lo, qh[c * 8 + jj * 2], accd);
                    accd = fmaf(hi, qh[c * 8 + jj * 2 + 1], accd);
                }
            }
            s = accd;
        }
        sc[h][j] = s;
    }
    __syncthreads();

    {
        int wv = tid >> 6, lane = tid & 63;
#pragma unroll
        for (int hh = 0; hh < 2; ++hh) {
            int h = wv + hh * 4;
            float s = sc[h][lane];
            float m = s;
#pragma unroll
            for (int off = 32; off; off >>= 1) m = fmaxf(m, __shfl_xor(m, off));
            float p = __expf(s - m);
            float sum = p;
#pragma unroll
            for (int off = 32; off; off >>= 1) sum += __shfl_xor(sum, off);
            sc[h][lane] = p / sum;
        }
    }
    __syncthreads();

    {
        int h = tid >> 5;
        const float* ph = sc[h];
        float a0 = 0.f, a1 = 0.f;
        const unsigned short* vbase = QKV + (size_t)b * 1536 + 1024 + 2 * tid;
#pragma unroll 4
        for (int j = 0; j < total; ++j) {
            int kkj = kks[j];
            unsigned int u = *(const unsigned int*)&vbase[(size_t)kkj * (NB * 1536)];
            float p = ph[j];
            a0 = fmaf(p, __uint_as_float(u << 16), a0);
            a1 = fmaf(p, __uint_as_float(u & 0xFFFF0000u), a1);
        }
        unsigned int o = ((unsigned int)f2bf(a0)) | (((unsigned int)f2bf(a1)) << 16);
        *(unsigned int*)&ATT[(size_t)(qrow * NB + b) * D + 2 * tid] = o;
    }
}

// ---------------- final LN (width 1024) with permuted output ----------------
__global__ __launch_bounds__(256) void final_ln_k(const float* __restrict__ Yb,
                                                  const float* __restrict__ g,
                                                  const float* __restrict__ be,
                                                  float* __restrict__ out) {
    int row = blockIdx.x;
    int u = row >> 3, b = row & 7;
    const float* x = Yb + (size_t)row * OUTD;
    float v[4];
    float s = 0.f, ss = 0.f;
#pragma unroll
    for (int j = 0; j < 4; ++j) {
        v[j] = x[threadIdx.x + j * 256];
        s += v[j];
        ss = fmaf(v[j], v[j], ss);
    }
#pragma unroll
    for (int off = 32; off; off >>= 1) {
        s += __shfl_xor(s, off);
        ss += __shfl_xor(ss, off);
    }
    __shared__ float rs_[4], rss_[4];
    int w = threadIdx.x >> 6;
    if ((threadIdx.x & 63) == 0) {
        rs_[w] = s;
        rss_[w] = ss;
    }
    __syncthreads();
    s = rs_[0] + rs_[1] + rs_[2] + rs_[3];
    ss = rss_[0] + rss_[1] + rss_[2] + rss_[3];
    float mean = s * (1.f / OUTD);
    float var = ss * (1.f / OUTD) - mean * mean;
    float rstd = rsqrtf(var + 1e-5f);
    float* o = out + ((size_t)(b * 256 + u)) * OUTD;
#pragma unroll
    for (int j = 0; j < 4; ++j) {
        int col = threadIdx.x + j * 256;
        o[col] = (v[j] - mean) * rstd * g[col] + be[col];
    }
}

extern "C" void kernel_launch(void* const* d_in, const int* in_sizes, int n_in, void* d_out,
                              int out_size, void* d_ws, size_t ws_size, hipStream_t stream) {
    (void)in_sizes;
    (void)n_in;
    (void)out_size;
    (void)ws_size;
    const float* input = (const float*)d_in[0];
    const int* lengths = (const int*)d_in[1];
    const float* w_in = (const float*)d_in[2];
    const float* ln_in_g = (const float*)d_in[3];
    const float* ln_in_b = (const float*)d_in[4];
    const float* wq = (const float*)d_in[5];
    const float* bq = (const float*)d_in[6];
    const float* wk = (const float*)d_in[7];
    const float* bk = (const float*)d_in[8];
    const float* wv = (const float*)d_in[9];
    const float* bv = (const float*)d_in[10];
    const float* wo = (const float*)d_in[11];
    const float* bo = (const float*)d_in[12];
    const float* ff_g = (const float*)d_in[13];
    const float* ff_b = (const float*)d_in[14];
    const float* w1 = (const float*)d_in[15];
    const float* b1 = (const float*)d_in[16];
    const float* w2 = (const float*)d_in[17];
    const float* b2 = (const float*)d_in[18];
    const float* lo_g = (const float*)d_in[19];
    const float* lo_b = (const float*)d_in[20];
    const float* w_out = (const float*)d_in[21];
    const float* b_out = (const float*)d_in[22];
    const float* lng = (const float*)d_in[23];
    const float* lnb = (const float*)d_in[24];
    float* out = (float*)d_out;

    char* wsc = (char*)d_ws;
    size_t off = 0;
    auto alloc = [&](size_t bytes) {
        char* p = wsc + off;
        off += (bytes + 255) & ~(size_t)255;
        return p;
    };
    unsigned short* ACT16 = (unsigned short*)alloc(2688ULL * 512 * 2);
    unsigned short* ATT16 = (unsigned short*)alloc(2688ULL * 512 * 2);
    unsigned short* HB16 = (unsigned short*)alloc(2560ULL * 2048 * 2);
    unsigned short* QKVB = (unsigned short*)alloc(2688ULL * 1536 * 2);
    float* SB = (float*)alloc(2560ULL * 512 * 4);
    unsigned short* WQKV16 = (unsigned short*)alloc(8ULL * 1536 * 512 * 2);
    unsigned short* WO16 = (unsigned short*)alloc(8ULL * 512 * 512 * 2);
    unsigned short* W1T = (unsigned short*)alloc(8ULL * 2048 * 512 * 2);
    unsigned short* W2T = (unsigned short*)alloc(8ULL * 512 * 2048 * 2);
    unsigned short* WOUT16 = (unsigned short*)alloc(1024ULL * 512 * 2);
    float* BQKV = (float*)alloc(8ULL * 1536 * 4);
    int* LRW = (int*)alloc(64);

    unsigned short* MEMS16 = ACT16;             // 120 rows
    unsigned short* LNB16 = ACT16 + 120 * 512;  // 2560 rows -> A has 2680 rows total
    float* XB = (float*)QKVB;    // init-time alias
    float* OUTB = (float*)QKVB;  // post-attention alias
    float* HBf = (float*)QKVB;   // final-proj alias

    lr_k<<<1, 64, 0, stream>>>(lengths, LRW, out + (size_t)NB * 256 * 1024);
    convw_all_k<<<LAYERS * 768 + 128, 256, 0, stream>>>(wq, wk, wv, wo, w1, w2, bq, bk, bv,
                                                        w_out, WQKV16, WO16, W1T, W2T, WOUT16,
                                                        BQKV);
    inproj_k<<<TR * NB, 128, 0, stream>>>(input, w_in, XB);
    initstate_k<<<SROWS * NB, 256, 0, stream>>>(XB, SB);
    mems0_k<<<15 * NB, 256, 0, stream>>>(XB, MEMS16);

    for (int l = 0; l < LAYERS; ++l) {
        if (l == 0) {
            ln2_k<<<SROWS * NB, 256, 0, stream>>>(SB, LNB16, ln_in_g, ln_in_b, nullptr, nullptr,
                                                  0);
        } else {
            // fused: SB = LN_lo(l-1)(SB); LNB16 = LN_in(l)(SB)
            ln2_k<<<SROWS * NB, 256, 0, stream>>>(SB, LNB16, lo_g + (l - 1) * D,
                                                  lo_b + (l - 1) * D, ln_in_g + l * D,
                                                  ln_in_b + l * D, 1);
        }
        // fused QKV: A = [MEMS][LN] (2680 rows), N = 1536; summary rows derived in attn
        gemm16_k<<<dim3(24, 42, 1), 256, 0, stream>>>(ACT16, WQKV16 + (size_t)l * 1536 * 512,
                                                      BQKV + l * 1536, QKVB, 2680, 1536, 512,
                                                      512, 4);
        attn_k<<<dim3(QN, NB), 256, 0, stream>>>(QKVB, ATT16, LRW);
        gemm16_k<<<dim3(8, 42, 1), 256, 0, stream>>>(ATT16, WO16 + (size_t)l * 512 * 512,
                                                     bo + l * D, OUTB, QN * NB, D, D, 512, 0);
        ln_res_k<<<(SROWS + 15) * NB, 256, 0, stream>>>(OUTB, SB, MEMS16, LNB16, ff_g + l * D,
                                                        ff_b + l * D);
        gemm16_k<<<dim3(32, 40, 1), 256, 0, stream>>>(LNB16, W1T + (size_t)l * 2048 * 512,
                                                      b1 + l * FFN_D, HB16, SROWS * NB, FFN_D,
                                                      512, 512, 1 | 4);
        gemm16_k<<<dim3(8, 40, 4), 256, 0, stream>>>(HB16, W2T + (size_t)l * 512 * 2048,
                                                     b2 + l * D, SB, SROWS * NB, D, FFN_D, 512,
                                                     8);
    }
    // last LN_lo -> LNB16 (bf16) for the final projection
    ln2_k<<<SROWS * NB, 256, 0, stream>>>(SB, LNB16, lo_g + 7 * D, lo_b + 7 * D, nullptr,
                                          nullptr, 0);
    gemm16_k<<<dim3(16, 32, 1), 256, 0, stream>>>(LNB16 + (size_t)RT * NB * D, WOUT16, b_out,
                                                  HBf, UU * NB, OUTD, 512, 512, 0);
    final_ln_k<<<UU * NB, 256, 0, stream>>>(HBf, lng, lnb, out);
}

// Round 9
// 1075.906 us; speedup vs baseline: 1.0929x; 1.0929x over previous
//
#include <hip/hip_runtime.h>
#include <math.h>

#define NB 8
#define D 512
#define H 8
#define DH 64
#define NSEG 16
#define RT 64
#define UU 256
#define QN 336
#define KN 335
#define SROWS 320
#define FFN_D 2048
#define LAYERS 8
#define OUTD 1024
#define TR 260
#define NEGV (-100000000.0f)
#define QSCALE 0.125f

typedef __attribute__((ext_vector_type(8))) short bf16x8;
typedef __attribute__((ext_vector_type(4))) float f32x4;

__device__ inline unsigned short f2bf(float f) {
    union { float f; unsigned int u; } v; v.f = f;
    unsigned int u = v.u;
    unsigned int r = (u + 0x7FFFu + ((u >> 16) & 1u)) >> 16;
    return (unsigned short)r;
}
__device__ inline float bf2f(unsigned short h) {
    union { unsigned int u; float f; } v; v.u = ((unsigned int)h) << 16;
    return v.f;
}

// 16-byte global -> LDS async DMA. LDS dest = wave-uniform base + lane*16.
__device__ inline void async16(const void* g, void* l) {
    __builtin_amdgcn_global_load_lds((const __attribute__((address_space(1))) void*)g,
                                     (__attribute__((address_space(3))) void*)l, 16, 0, 0);
}

// ---------------- input projection + reshape to (t,b,512) ----------------
__global__ __launch_bounds__(128) void inproj_k(const float* __restrict__ input,
                                                const float* __restrict__ w_in,
                                                float* __restrict__ XB) {
    __shared__ float wl[80 * 128];
    __shared__ float il[4 * 80];
    int tid = threadIdx.x;
    int t = blockIdx.x >> 3;
    int b = blockIdx.x & 7;
    for (int i = tid; i < 80 * 128; i += 128) wl[i] = w_in[i];
    const float* inp = input + ((size_t)b * 1040 + (size_t)t * 4) * 80;
    for (int i = tid; i < 320; i += 128) il[i] = inp[i];
    __syncthreads();
    float* xrow = XB + ((size_t)(t * NB + b)) * D;
#pragma unroll
    for (int c = 0; c < 4; ++c) {
        float acc = 0.f;
        for (int i = 0; i < 80; ++i) acc = fmaf(il[c * 80 + i], wl[i * 128 + tid], acc);
        xrow[c * 128 + tid] = acc;
    }
}

// ---------------- init state S = [rc(64), utt(256)] (fp32) + initial mems (bf16) -------
__global__ __launch_bounds__(256) void init2_k(const float* __restrict__ XB,
                                               float* __restrict__ S,
                                               unsigned short* __restrict__ MEMS) {
    int r = blockIdx.x;
    if (r < SROWS * NB) {
        int srow = r >> 3, b = r & 7;
        int src;
        if (srow < RT) {
            int i = srow >> 2, jj = srow & 3;
            src = (i < 15 ? (i + 1) * 16 : 256) + jj;
        } else {
            src = srow - RT;
        }
        const float* xr = XB + ((size_t)(src * NB + b)) * D;
        float* sr = S + (size_t)r * D;
        sr[threadIdx.x] = xr[threadIdx.x];
        sr[threadIdx.x + 256] = xr[threadIdx.x + 256];
        return;
    }
    int ib = r - SROWS * NB;  // 0..119
    int i = ib >> 3, b = ib & 7;
    for (int c = 0; c < 2; ++c) {
        int col = threadIdx.x + c * 256;
        float s = 0.f;
#pragma unroll
        for (int t = 0; t < 16; ++t) s += XB[((size_t)((i * 16 + t) * NB + b)) * D + col];
        MEMS[(size_t)ib * D + col] = f2bf(s * (1.f / 16.f));
    }
}

// ---------------- fused double-LayerNorm ----------------
// fused=0: Y16 = LN_A(X), X untouched.
// fused=1: t = LN_A(X); X = t; Y16 = LN_B(t).
__global__ __launch_bounds__(256) void ln2_k(float* __restrict__ X,
                                             unsigned short* __restrict__ Y16,
                                             const float* __restrict__ gA,
                                             const float* __restrict__ bA,
                                             const float* __restrict__ gB,
                                             const float* __restrict__ bB, int fused) {
    int row = blockIdx.x;
    float* x = X + (size_t)row * D;
    __shared__ float rs_[4], rss_[4], rs2[4], rss2[4];
    int w = threadIdx.x >> 6;
    float v[2];
    float s = 0.f, ss = 0.f;
#pragma unroll
    for (int j = 0; j < 2; ++j) {
        v[j] = x[threadIdx.x + j * 256];
        s += v[j];
        ss = fmaf(v[j], v[j], ss);
    }
#pragma unroll
    for (int off = 32; off; off >>= 1) {
        s += __shfl_xor(s, off);
        ss += __shfl_xor(ss, off);
    }
    if ((threadIdx.x & 63) == 0) { rs_[w] = s; rss_[w] = ss; }
    __syncthreads();
    s = rs_[0] + rs_[1] + rs_[2] + rs_[3];
    ss = rss_[0] + rss_[1] + rss_[2] + rss_[3];
    float mean = s * (1.f / D);
    float var = ss * (1.f / D) - mean * mean;
    float rstd = rsqrtf(var + 1e-5f);
    float y1[2];
#pragma unroll
    for (int j = 0; j < 2; ++j) {
        int col = threadIdx.x + j * 256;
        y1[j] = (v[j] - mean) * rstd * gA[col] + bA[col];
    }
    if (!fused) {
#pragma unroll
        for (int j = 0; j < 2; ++j)
            Y16[(size_t)row * D + threadIdx.x + j * 256] = f2bf(y1[j]);
        return;
    }
    float s2 = 0.f, ss2 = 0.f;
#pragma unroll
    for (int j = 0; j < 2; ++j) {
        s2 += y1[j];
        ss2 = fmaf(y1[j], y1[j], ss2);
    }
#pragma unroll
    for (int off = 32; off; off >>= 1) {
        s2 += __shfl_xor(s2, off);
        ss2 += __shfl_xor(ss2, off);
    }
    if ((threadIdx.x & 63) == 0) { rs2[w] = s2; rss2[w] = ss2; }
    __syncthreads();
    s2 = rs2[0] + rs2[1] + rs2[2] + rs2[3];
    ss2 = rss2[0] + rss2[1] + rss2[2] + rss2[3];
    float mean2 = s2 * (1.f / D);
    float var2 = ss2 * (1.f / D) - mean2 * mean2;
    float rstd2 = rsqrtf(var2 + 1e-5f);
#pragma unroll
    for (int j = 0; j < 2; ++j) {
        int col = threadIdx.x + j * 256;
        x[col] = y1[j];
        Y16[(size_t)row * D + col] = f2bf((y1[j] - mean2) * rstd2 * gB[col] + bB[col]);
    }
}

// ---------------- residual add + LN + mems-tanh fused ----------------
__global__ __launch_bounds__(256) void ln_res_k(const float* __restrict__ OUTB,
                                                float* __restrict__ SB,
                                                unsigned short* __restrict__ MEMS,
                                                unsigned short* __restrict__ Y16,
                                                const float* __restrict__ g,
                                                const float* __restrict__ be) {
    int row = blockIdx.x;
    if (row >= SROWS * NB) {
        int j = row - SROWS * NB;
#pragma unroll
        for (int c = 0; c < 2; ++c) {
            int col = threadIdx.x + c * 256;
            MEMS[(size_t)j * D + col] = f2bf(tanhf(OUTB[(size_t)row * D + col]));
        }
        return;
    }
    float v[2];
    float s = 0.f, ss = 0.f;
#pragma unroll
    for (int j = 0; j < 2; ++j) {
        int col = threadIdx.x + j * 256;
        float r = SB[(size_t)row * D + col] + OUTB[(size_t)row * D + col];
        SB[(size_t)row * D + col] = r;
        v[j] = r;
        s += r;
        ss = fmaf(r, r, ss);
    }
#pragma unroll
    for (int off = 32; off; off >>= 1) {
        s += __shfl_xor(s, off);
        ss += __shfl_xor(ss, off);
    }
    __shared__ float rs_[4], rss_[4];
    int w = threadIdx.x >> 6;
    if ((threadIdx.x & 63) == 0) {
        rs_[w] = s;
        rss_[w] = ss;
    }
    __syncthreads();
    s = rs_[0] + rs_[1] + rs_[2] + rs_[3];
    ss = rss_[0] + rss_[1] + rss_[2] + rss_[3];
    float mean = s * (1.f / D);
    float var = ss * (1.f / D) - mean * mean;
    float rstd = rsqrtf(var + 1e-5f);
#pragma unroll
    for (int j = 0; j < 2; ++j) {
        int col = threadIdx.x + j * 256;
        Y16[(size_t)row * D + col] = f2bf((v[j] - mean) * rstd * g[col] + be[col]);
    }
}

// ---------------- 64x64 transpose + fp32->bf16 convert helper ----------------
__device__ inline void conv_tile64(float (*tile)[65], const float* __restrict__ src, int srcN,
                                   int k0, int sn0, unsigned short* __restrict__ dst, int dstK,
                                   int dn0) {
    int t = threadIdx.x;
#pragma unroll
    for (int p = 0; p < 4; ++p) {
        int r = p * 16 + (t >> 4);
        int c = (t & 15) * 4;
        *(float4*)&tile[r][c] = *(const float4*)&src[(size_t)(k0 + r) * srcN + sn0 + c];
    }
    __syncthreads();
#pragma unroll
    for (int p = 0; p < 2; ++p) {
        int rn = p * 32 + (t >> 3);
        int kc = (t & 7) * 8;
        int4 o;
        o.x = (int)f2bf(tile[kc + 0][rn]) | ((int)f2bf(tile[kc + 1][rn]) << 16);
        o.y = (int)f2bf(tile[kc + 2][rn]) | ((int)f2bf(tile[kc + 3][rn]) << 16);
        o.z = (int)f2bf(tile[kc + 4][rn]) | ((int)f2bf(tile[kc + 5][rn]) << 16);
        o.w = (int)f2bf(tile[kc + 6][rn]) | ((int)f2bf(tile[kc + 7][rn]) << 16);
        *(int4*)&dst[(size_t)(dn0 + rn) * dstK + k0 + kc] = o;
    }
    __syncthreads();
}

// ---------------- ALL-layer weight conversion (one shot) + lr ----------
__global__ __launch_bounds__(256) void convw_all_k(const float* __restrict__ wq,
                                                   const float* __restrict__ wk,
                                                   const float* __restrict__ wv,
                                                   const float* __restrict__ wo,
                                                   const float* __restrict__ w1,
                                                   const float* __restrict__ w2,
                                                   const float* __restrict__ bq,
                                                   const float* __restrict__ bk,
                                                   const float* __restrict__ bv,
                                                   const float* __restrict__ w_out,
                                                   unsigned short* __restrict__ WQKV,
                                                   unsigned short* __restrict__ WO16,
                                                   unsigned short* __restrict__ W1T,
                                                   unsigned short* __restrict__ W2T,
                                                   unsigned short* __restrict__ WOUT16,
                                                   float* __restrict__ BQKV,
                                                   const int* __restrict__ lengths,
                                                   int* __restrict__ lrw,
                                                   float* __restrict__ out_lr) {
    __shared__ float tile[64][65];
    int tb = blockIdx.x;
    if (tb >= LAYERS * 768 + 128) {
        if (threadIdx.x == 0) {
            int mx = 0;
            for (int b = 0; b < NB; ++b) {
                int v = lengths[b] >> 2;
                lrw[b] = v;
                out_lr[b] = (float)v;
                if (v > mx) mx = v;
            }
            lrw[NB] = mx;
        }
        return;
    }
    if (tb >= LAYERS * 768) {
        int t = tb - LAYERS * 768;
        int n0 = (t % 16) * 64, k0 = (t / 16) * 64;
        conv_tile64(tile, w_out, 1024, k0, n0, WOUT16, 512, n0);
        return;
    }
    int l = tb / 768, t = tb % 768;
    if (t == 0) {
        for (int i = threadIdx.x; i < 1536; i += 256)
            BQKV[l * 1536 + i] = i < 512 ? bq[l * 512 + i]
                                         : (i < 1024 ? bk[l * 512 + i - 512]
                                                     : bv[l * 512 + i - 1024]);
    }
    if (t < 192) {
        int n0 = (t % 24) * 64, k0 = (t / 24) * 64;
        const float* src;
        int sn0;
        if (n0 < 512) { src = wq + (size_t)l * 262144; sn0 = n0; }
        else if (n0 < 1024) { src = wk + (size_t)l * 262144; sn0 = n0 - 512; }
        else { src = wv + (size_t)l * 262144; sn0 = n0 - 1024; }
        conv_tile64(tile, src, 512, k0, sn0, WQKV + (size_t)l * 1536 * 512, 512, n0);
    } else if (t < 256) {
        int tt = t - 192;
        int n0 = (tt % 8) * 64, k0 = (tt / 8) * 64;
        conv_tile64(tile, wo + (size_t)l * 262144, 512, k0, n0, WO16 + (size_t)l * 512 * 512, 512,
                    n0);
    } else if (t < 512) {
        int tt = t - 256;
        int n0 = (tt % 32) * 64, k0 = (tt / 32) * 64;
        conv_tile64(tile, w1 + (size_t)l * 1048576, 2048, k0, n0, W1T + (size_t)l * 2048 * 512,
                    512, n0);
    } else {
        int tt = t - 512;
        int n0 = (tt % 8) * 64, k0 = (tt / 8) * 64;
        conv_tile64(tile, w2 + (size_t)l * 1048576, 512, k0, n0, W2T + (size_t)l * 512 * 2048,
                    2048, n0);
    }
}

// ---------------- bf16 MFMA GEMM, 64x64 tile, BK=64, async LDS + XOR swizzle ----------
// Round-5 proven structure: single buffer, 16 KB LDS -> 8 blocks/CU (full 32 waves);
// inter-block co-residency hides the barrier drain (m114). Do NOT double-buffer (r8)
// or widen BK (r7) or the tile (r6): all three cut occupancy and regressed.
// flags: 1 = relu, 2 = add into fp32 C, 4 = bf16 output, 8 = atomicAdd into fp32 C
__global__ __launch_bounds__(256) void gemm16_k(const unsigned short* __restrict__ A,
                                                const unsigned short* __restrict__ BT,
                                                const float* __restrict__ bias,
                                                void* __restrict__ Cp, int M, int N, int K,
                                                int Kchunk, int flags) {
    __shared__ unsigned short As[64 * 64];
    __shared__ unsigned short Bs[64 * 64];
    int tid = threadIdx.x;
    int wave = tid >> 6, lane = tid & 63;
    int wm = wave >> 1, wn = wave & 1;
    int quad = lane >> 4, sub = lane & 15;
    int m0 = blockIdx.y * 64, n0 = blockIdx.x * 64;
    int kb = blockIdx.z * Kchunk;

    int s0 = wave * 128 + lane;
    int s1 = s0 + 64;
    int r0 = s0 >> 3, c0 = (s0 & 7) ^ (r0 & 7);
    int r1 = s1 >> 3, c1 = (s1 & 7) ^ (r1 & 7);
    int gra0 = m0 + r0; if (gra0 >= M) gra0 = M - 1;  // clamp: stores row-guarded
    int gra1 = m0 + r1; if (gra1 >= M) gra1 = M - 1;
    const unsigned short* gA0 = A + (size_t)gra0 * K + kb + c0 * 8;
    const unsigned short* gA1 = A + (size_t)gra1 * K + kb + c1 * 8;
    const unsigned short* gB0 = BT + (size_t)(n0 + r0) * K + kb + c0 * 8;
    const unsigned short* gB1 = BT + (size_t)(n0 + r1) * K + kb + c1 * 8;
    unsigned short* lA0 = &As[(wave * 128) * 8];
    unsigned short* lA1 = &As[(wave * 128 + 64) * 8];
    unsigned short* lB0 = &Bs[(wave * 128) * 8];
    unsigned short* lB1 = &Bs[(wave * 128 + 64) * 8];

    int rowA0 = wm * 32 + sub, rowA1 = rowA0 + 16;
    int rowB0 = wn * 32 + sub, rowB1 = rowB0 + 16;

    f32x4 acc[2][2] = {};
    for (int k0 = 0; k0 < Kchunk; k0 += 64) {
        async16(gA0 + k0, lA0);
        async16(gA1 + k0, lA1);
        async16(gB0 + k0, lB0);
        async16(gB1 + k0, lB1);
        __syncthreads();
#pragma unroll
        for (int ks = 0; ks < 2; ++ks) {
            int cc = ks * 4 + quad;
            bf16x8 af0 = *(const bf16x8*)&As[rowA0 * 64 + ((cc ^ (rowA0 & 7)) * 8)];
            bf16x8 af1 = *(const bf16x8*)&As[rowA1 * 64 + ((cc ^ (rowA1 & 7)) * 8)];
            bf16x8 bf0 = *(const bf16x8*)&Bs[rowB0 * 64 + ((cc ^ (rowB0 & 7)) * 8)];
            bf16x8 bf1 = *(const bf16x8*)&Bs[rowB1 * 64 + ((cc ^ (rowB1 & 7)) * 8)];
            acc[0][0] = __builtin_amdgcn_mfma_f32_16x16x32_bf16(af0, bf0, acc[0][0], 0, 0, 0);
            acc[0][1] = __builtin_amdgcn_mfma_f32_16x16x32_bf16(af0, bf1, acc[0][1], 0, 0, 0);
            acc[1][0] = __builtin_amdgcn_mfma_f32_16x16x32_bf16(af1, bf0, acc[1][0], 0, 0, 0);
            acc[1][1] = __builtin_amdgcn_mfma_f32_16x16x32_bf16(af1, bf1, acc[1][1], 0, 0, 0);
        }
        __syncthreads();
    }

    bool relu = flags & 1, addc = flags & 2, obf = flags & 4, atom = flags & 8;
    bool addbias = !atom || blockIdx.z == 0;
    float* Cf = (float*)Cp;
    unsigned short* Ch = (unsigned short*)Cp;
#pragma unroll
    for (int mi = 0; mi < 2; ++mi) {
#pragma unroll
        for (int ni = 0; ni < 2; ++ni) {
#pragma unroll
            for (int r = 0; r < 4; ++r) {
                int row = m0 + wm * 32 + mi * 16 + quad * 4 + r;
                int col = n0 + wn * 32 + ni * 16 + sub;
                if (row < M) {
                    float v = acc[mi][ni][r] + (addbias ? bias[col] : 0.f);
                    if (relu) v = fmaxf(v, 0.f);
                    size_t idx = (size_t)row * N + col;
                    if (obf) {
                        Ch[idx] = f2bf(v);
                    } else if (atom) {
                        atomicAdd(&Cf[idx], v);
                    } else {
                        if (addc) v += Cf[idx];
                        Cf[idx] = v;
                    }
                }
            }
        }
    }
}

// ---------------- attention: one 256-thread block per (qrow, b), all 8 heads -------------
// Summary (is_sum) q-rows are computed on the fly as the mean of the 16 utt Q rows
// (mean(x)@Wq + bq == mean(x@Wq + bq)), so no summary GEMM rows are needed.
__global__ __launch_bounds__(256) void attn_k(const unsigned short* __restrict__ QKV,
                                              unsigned short* __restrict__ ATT,
                                              const int* __restrict__ lrw) {
    int tid = threadIdx.x;
    int qrow = blockIdx.x;
    int b = blockIdx.y;

    int i, is_sum;
    if (qrow < RT) {
        i = qrow >> 2;
        is_sum = 0;
    } else if (qrow < RT + UU) {
        i = (qrow - RT) >> 4;
        is_sum = 0;
    } else {
        i = qrow - (RT + UU);
        is_sum = 1;
    }
    int ms = (i > 4) ? (i - 4) : 0;
    int n_mem = is_sum ? 0 : (i - ms);
    int us = (i * 16 - 32 > 0) ? (i * 16 - 32) : 0;
    int ue = (i + 1) * 16;
    int total = n_mem + 4 + (ue - us);
    int klen = KN + lrw[b] - lrw[NB];

    __shared__ float qs[512];
    __shared__ float sc[H][64];
    __shared__ int kks[64];

    if (!is_sum) {
        const unsigned int* qrp =
            (const unsigned int*)&QKV[(size_t)(120 + qrow * NB + b) * 1536];
        unsigned int u = qrp[tid];
        qs[2 * tid] = __uint_as_float(u << 16) * QSCALE;
        qs[2 * tid + 1] = __uint_as_float(u & 0xFFFF0000u) * QSCALE;
    } else {
        const unsigned int* qrp =
            (const unsigned int*)&QKV[(size_t)(120 + (RT + i * 16) * NB + b) * 1536];
        float a0 = 0.f, a1 = 0.f;
#pragma unroll
        for (int t = 0; t < 16; ++t) {
            unsigned int u = qrp[(size_t)t * (NB * 768) + tid];
            a0 += __uint_as_float(u << 16);
            a1 += __uint_as_float(u & 0xFFFF0000u);
        }
        qs[2 * tid] = a0 * (QSCALE / 16.f);
        qs[2 * tid + 1] = a1 * (QSCALE / 16.f);
    }
    if (tid < 64) {
        int kk = -1;
        if (tid < total) {
            if (tid < n_mem)
                kk = ms + tid;
            else if (tid < n_mem + 4)
                kk = 15 + i * 4 + (tid - n_mem);
            else
                kk = 79 + us + (tid - n_mem - 4);
        }
        kks[tid] = kk;
    }
    __syncthreads();

#pragma unroll
    for (int rep = 0; rep < 2; ++rep) {
        int p = rep * 256 + tid;
        int h = p >> 6, j = p & 63;
        int kk = kks[j];
        float s = NEGV;
        if (kk >= 0 && kk < klen) {
            const int4* kr = (const int4*)&QKV[(size_t)(kk * NB + b) * 1536 + 512 + h * DH];
            const float* qh = &qs[h * DH];
            float accd = 0.f;
#pragma unroll
            for (int c = 0; c < 8; ++c) {
                int4 kv = kr[c];
                const int uu[4] = {kv.x, kv.y, kv.z, kv.w};
#pragma unroll
                for (int jj = 0; jj < 4; ++jj) {
                    float lo = __uint_as_float(((unsigned)uu[jj]) << 16);
                    float hi = __uint_as_float(((unsigned)uu[jj]) & 0xFFFF0000u);
                    accd = fmaf(lo, qh[c * 8 + jj * 2], accd);
                    accd = fmaf(hi, qh[c * 8 + jj * 2 + 1], accd);
                }
            }
            s = accd;
        }
        sc[h][j] = s;
    }
    __syncthreads();

    {
        int wv = tid >> 6, lane = tid & 63;
#pragma unroll
        for (int hh = 0; hh < 2; ++hh) {
            int h = wv + hh * 4;
            float s = sc[h][lane];
            float m = s;
#pragma unroll
            for (int off = 32; off; off >>= 1) m = fmaxf(m, __shfl_xor(m, off));
            float p = __expf(s - m);
            float sum = p;
#pragma unroll
            for (int off = 32; off; off >>= 1) sum += __shfl_xor(sum, off);
            sc[h][lane] = p / sum;
        }
    }
    __syncthreads();

    {
        int h = tid >> 5;
        const float* ph = sc[h];
        float a0 = 0.f, a1 = 0.f;
        const unsigned short* vbase = QKV + (size_t)b * 1536 + 1024 + 2 * tid;
#pragma unroll 4
        for (int j = 0; j < total; ++j) {
            int kkj = kks[j];
            unsigned int u = *(const unsigned int*)&vbase[(size_t)kkj * (NB * 1536)];
            float p = ph[j];
            a0 = fmaf(p, __uint_as_float(u << 16), a0);
            a1 = fmaf(p, __uint_as_float(u & 0xFFFF0000u), a1);
        }
        unsigned int o = ((unsigned int)f2bf(a0)) | (((unsigned int)f2bf(a1)) << 16);
        *(unsigned int*)&ATT[(size_t)(qrow * NB + b) * D + 2 * tid] = o;
    }
}

// ---------------- final LN (width 1024) with permuted output ----------------
__global__ __launch_bounds__(256) void final_ln_k(const float* __restrict__ Yb,
                                                  const float* __restrict__ g,
                                                  const float* __restrict__ be,
                                                  float* __restrict__ out) {
    int row = blockIdx.x;
    int u = row >> 3, b = row & 7;
    const float* x = Yb + (size_t)row * OUTD;
    float v[4];
    float s = 0.f, ss = 0.f;
#pragma unroll
    for (int j = 0; j < 4; ++j) {
        v[j] = x[threadIdx.x + j * 256];
        s += v[j];
        ss = fmaf(v[j], v[j], ss);
    }
#pragma unroll
    for (int off = 32; off; off >>= 1) {
        s += __shfl_xor(s, off);
        ss += __shfl_xor(ss, off);
    }
    __shared__ float rs_[4], rss_[4];
    int w = threadIdx.x >> 6;
    if ((threadIdx.x & 63) == 0) {
        rs_[w] = s;
        rss_[w] = ss;
    }
    __syncthreads();
    s = rs_[0] + rs_[1] + rs_[2] + rs_[3];
    ss = rss_[0] + rss_[1] + rss_[2] + rss_[3];
    float mean = s * (1.f / OUTD);
    float var = ss * (1.f / OUTD) - mean * mean;
    float rstd = rsqrtf(var + 1e-5f);
    float* o = out + ((size_t)(b * 256 + u)) * OUTD;
#pragma unroll
    for (int j = 0; j < 4; ++j) {
        int col = threadIdx.x + j * 256;
        o[col] = (v[j] - mean) * rstd * g[col] + be[col];
    }
}

extern "C" void kernel_launch(void* const* d_in, const int* in_sizes, int n_in, void* d_out,
                              int out_size, void* d_ws, size_t ws_size, hipStream_t stream) {
    (void)in_sizes;
    (void)n_in;
    (void)out_size;
    (void)ws_size;
    const float* input = (const float*)d_in[0];
    const int* lengths = (const int*)d_in[1];
    const float* w_in = (const float*)d_in[2];
    const float* ln_in_g = (const float*)d_in[3];
    const float* ln_in_b = (const float*)d_in[4];
    const float* wq = (const float*)d_in[5];
    const float* bq = (const float*)d_in[6];
    const float* wk = (const float*)d_in[7];
    const float* bk = (const float*)d_in[8];
    const float* wv = (const float*)d_in[9];
    const float* bv = (const float*)d_in[10];
    const float* wo = (const float*)d_in[11];
    const float* bo = (const float*)d_in[12];
    const float* ff_g = (const float*)d_in[13];
    const float* ff_b = (const float*)d_in[14];
    const float* w1 = (const float*)d_in[15];
    const float* b1 = (const float*)d_in[16];
    const float* w2 = (const float*)d_in[17];
    const float* b2 = (const float*)d_in[18];
    const float* lo_g = (const float*)d_in[19];
    const float* lo_b = (const float*)d_in[20];
    const float* w_out = (const float*)d_in[21];
    const float* b_out = (const float*)d_in[22];
    const float* lng = (const float*)d_in[23];
    const float* lnb = (const float*)d_in[24];
    float* out = (float*)d_out;

    char* wsc = (char*)d_ws;
    size_t off = 0;
    auto alloc = [&](size_t bytes) {
        char* p = wsc + off;
        off += (bytes + 255) & ~(size_t)255;
        return p;
    };
    unsigned short* ACT16 = (unsigned short*)alloc(2688ULL * 512 * 2);
    unsigned short* ATT16 = (unsigned short*)alloc(2688ULL * 512 * 2);
    unsigned short* HB16 = (unsigned short*)alloc(2560ULL * 2048 * 2);
    unsigned short* QKVB = (unsigned short*)alloc(2688ULL * 1536 * 2);
    float* SB = (float*)alloc(2560ULL * 512 * 4);
    unsigned short* WQKV16 = (unsigned short*)alloc(8ULL * 1536 * 512 * 2);
    unsigned short* WO16 = (unsigned short*)alloc(8ULL * 512 * 512 * 2);
    unsigned short* W1T = (unsigned short*)alloc(8ULL * 2048 * 512 * 2);
    unsigned short* W2T = (unsigned short*)alloc(8ULL * 512 * 2048 * 2);
    unsigned short* WOUT16 = (unsigned short*)alloc(1024ULL * 512 * 2);
    float* BQKV = (float*)alloc(8ULL * 1536 * 4);
    int* LRW = (int*)alloc(64);

    unsigned short* MEMS16 = ACT16;             // 120 rows
    unsigned short* LNB16 = ACT16 + 120 * 512;  // 2560 rows -> A has 2680 rows total
    float* XB = (float*)QKVB;    // init-time alias
    float* OUTB = (float*)QKVB;  // post-attention alias
    float* HBf = (float*)QKVB;   // final-proj alias

    convw_all_k<<<LAYERS * 768 + 129, 256, 0, stream>>>(
        wq, wk, wv, wo, w1, w2, bq, bk, bv, w_out, WQKV16, WO16, W1T, W2T, WOUT16, BQKV, lengths,
        LRW, out + (size_t)NB * 256 * 1024);
    inproj_k<<<TR * NB, 128, 0, stream>>>(input, w_in, XB);
    init2_k<<<(SROWS + 15) * NB, 256, 0, stream>>>(XB, SB, MEMS16);

    for (int l = 0; l < LAYERS; ++l) {
        if (l == 0) {
            ln2_k<<<SROWS * NB, 256, 0, stream>>>(SB, LNB16, ln_in_g, ln_in_b, nullptr, nullptr,
                                                  0);
        } else {
            // fused: SB = LN_lo(l-1)(SB); LNB16 = LN_in(l)(SB)
            ln2_k<<<SROWS * NB, 256, 0, stream>>>(SB, LNB16, lo_g + (l - 1) * D,
                                                  lo_b + (l - 1) * D, ln_in_g + l * D,
                                                  ln_in_b + l * D, 1);
        }
        // fused QKV: A = [MEMS][LN] (2680 rows), N = 1536; summary rows derived in attn
        gemm16_k<<<dim3(24, 42, 1), 256, 0, stream>>>(ACT16, WQKV16 + (size_t)l * 1536 * 512,
                                                      BQKV + l * 1536, QKVB, 2680, 1536, 512,
                                                      512, 4);
        attn_k<<<dim3(QN, NB), 256, 0, stream>>>(QKVB, ATT16, LRW);
        gemm16_k<<<dim3(8, 42, 1), 256, 0, stream>>>(ATT16, WO16 + (size_t)l * 512 * 512,
                                                     bo + l * D, OUTB, QN * NB, D, D, 512, 0);
        ln_res_k<<<(SROWS + 15) * NB, 256, 0, stream>>>(OUTB, SB, MEMS16, LNB16, ff_g + l * D,
                                                        ff_b + l * D);
        gemm16_k<<<dim3(32, 40, 1), 256, 0, stream>>>(LNB16, W1T + (size_t)l * 2048 * 512,
                                                      b1 + l * FFN_D, HB16, SROWS * NB, FFN_D,
                                                      512, 512, 1 | 4);
        gemm16_k<<<dim3(8, 40, 4), 256, 0, stream>>>(HB16, W2T + (size_t)l * 512 * 2048,
                                                     b2 + l * D, SB, SROWS * NB, D, FFN_D, 512,
                                                     8);
    }
    // last LN_lo -> LNB16 (bf16) for the final projection
    ln2_k<<<SROWS * NB, 256, 0, stream>>>(SB, LNB16, lo_g + 7 * D, lo_b + 7 * D, nullptr,
                                          nullptr, 0);
    gemm16_k<<<dim3(16, 32, 1), 256, 0, stream>>>(LNB16 + (size_t)RT * NB * D, WOUT16, b_out,
                                                  HBf, UU * NB, OUTD, 512, 512, 0);
    final_ln_k<<<UU * NB, 256, 0, stream>>>(HBf, lng, lnb, out);
}